// Round 1
// baseline (129.742 us; speedup 1.0000x reference)
//
#include <hip/hip_runtime.h>

#define NTOT   131072
#define DIMV   512
#define GCNT   512
#define NGRP   256
#define KMARG  0.02f
#define CMARG  2.0f
#define EPSC   1e-6f

__device__ __forceinline__ float wave_sum(float v) {
#pragma unroll
  for (int off = 32; off; off >>= 1) v += __shfl_down(v, off, 64);
  return v;
}

// Block-wide broadcast sum. NW = number of wave64s in the block.
template <int NW>
__device__ __forceinline__ float block_sum(float v, float* red) {
  const int t = threadIdx.x;
  v = wave_sum(v);
  __syncthreads();                 // WAR guard on red from previous call
  if ((t & 63) == 0) red[t >> 6] = v;
  __syncthreads();
  float s = 0.0f;
#pragma unroll
  for (int i = 0; i < NW; ++i) s += red[i];
  return s;
}

// One wave (64 lanes) per row; 4 rows per 256-thread block.
// Each lane: 2x float4 from each operand -> 8 MACs -> wave shuffle reduce.
__global__ __launch_bounds__(256) void dot_kernel(const float* __restrict__ zr,
                                                  const float* __restrict__ zv,
                                                  float* __restrict__ dout) {
  const int wave = threadIdx.x >> 6;
  const int lane = threadIdx.x & 63;
  const int row  = (blockIdx.x << 2) + wave;
  const float4* r = (const float4*)zr + ((size_t)row << 7);  // 128 float4 / row
  const float4* v = (const float4*)zv + ((size_t)row << 7);
  float4 a0 = r[lane];
  float4 b0 = v[lane];
  float4 a1 = r[lane + 64];
  float4 b1 = v[lane + 64];
  float s = a0.x * b0.x + a0.y * b0.y + a0.z * b0.z + a0.w * b0.w +
            a1.x * b1.x + a1.y * b1.y + a1.z * b1.z + a1.w * b1.w;
  s = wave_sum(s);
  if (lane == 0) dout[row] = 1.0f - s;
}

// One 256-thread block per group.
__global__ __launch_bounds__(256) void group_kernel(const float* __restrict__ d,
                                                    const int* __restrict__ labels,
                                                    const int* __restrict__ varl,
                                                    float* __restrict__ gout) {
  __shared__ float red[4];
  __shared__ int   skey[NGRP];
  __shared__ float sval[NGRP];
  const int g = blockIdx.x, t = threadIdx.x;
  const int idx = g * NGRP + t;
  const float dv  = d[idx];
  const int   vli = varl[idx];
  const float vv  = (float)vli;
  const int   lab = labels[idx];

  // ---- label-partition partial sums (for db/dp means) ----
  const float sb = block_sum<4>((lab == 0) ? dv : 0.0f, red);
  const float cb = block_sum<4>((lab == 0) ? 1.0f : 0.0f, red);
  const float sp = block_sum<4>((lab == 1) ? dv : 0.0f, red);
  const float cp = block_sum<4>((lab == 1) ? 1.0f : 0.0f, red);

  // ---- corr (z-score matching) loss; std is unbiased (ddof=1) ----
  const float mv = block_sum<4>(vv, red) * (1.0f / NGRP);
  const float md = block_sum<4>(dv, red) * (1.0f / NGRP);
  const float vdev = vv - mv, ddev = dv - md;
  const float vvar = block_sum<4>(vdev * vdev, red) * (1.0f / (NGRP - 1));
  const float dvar = block_sum<4>(ddev * ddev, red) * (1.0f / (NGRP - 1));
  const float vstd = sqrtf(vvar), dstd = sqrtf(dvar);
  const float vz = vdev / (vstd + EPSC), dz = ddev / (dstd + EPSC);
  float corr = block_sum<4>((vz - dz) * (vz - dz), red) * (1.0f / NGRP);
  corr = (vstd > 0.0f && dstd > 0.0f) ? corr : 0.0f;

  // ---- stable sort by var_len: key = v*256 + orig_idx (emulates stable argsort) ----
  skey[t] = (vli << 8) | t;
  sval[t] = dv;
  __syncthreads();
  for (int k = 2; k <= NGRP; k <<= 1) {
    for (int j = k >> 1; j > 0; j >>= 1) {
      const int ixj = t ^ j;
      if (ixj > t) {
        const int k1 = skey[t], k2 = skey[ixj];
        const bool up = ((t & k) == 0);
        if (up ? (k1 > k2) : (k1 < k2)) {
          const float v1 = sval[t], v2 = sval[ixj];
          skey[t] = k2; skey[ixj] = k1;
          sval[t] = v2; sval[ixj] = v1;
        }
      }
      __syncthreads();
    }
  }

  // ---- neighbor monotonicity violation (mean over NG-1) ----
  float nv = 0.0f;
  if (t < NGRP - 1) nv = fmaxf(sval[t] - sval[t + 1] + KMARG, 0.0f);
  const float neigh = block_sum<4>(nv, red) * (1.0f / (NGRP - 1));

  // ---- pairwise rank loss: thread t = row i, uniform j loop (LDS broadcast) ----
  const int   vi = skey[t] >> 8;
  const float di = sval[t];
  float ps = 0.0f, pc = 0.0f;
  for (int jj = 0; jj < NGRP; ++jj) {
    const int   vj = skey[jj] >> 8;
    const float dj = sval[jj];
    if (vj > vi) {
      pc += 1.0f;
      ps += fmaxf(KMARG - (dj - di), 0.0f);
    }
  }
  const float PS = block_sum<4>(ps, red);
  const float PC = block_sum<4>(pc, red);
  const float rank = (PC > 0.0f) ? PS / fmaxf(PC, 1.0f) : 0.0f;

  if (t == 0) {
    gout[g]            = corr + neigh + rank;
    gout[GCNT + g]     = sb;
    gout[2 * GCNT + g] = sp;
    gout[3 * GCNT + g] = cb;
    gout[4 * GCNT + g] = cp;
  }
}

__global__ __launch_bounds__(512) void final_kernel(const float* __restrict__ gout,
                                                    float* __restrict__ out) {
  __shared__ float red[8];
  const int t = threadIdx.x;
  const float L  = block_sum<8>(gout[t], red);
  const float SB = block_sum<8>(gout[GCNT + t], red);
  const float SP = block_sum<8>(gout[2 * GCNT + t], red);
  const float CB = block_sum<8>(gout[3 * GCNT + t], red);
  const float CP = block_sum<8>(gout[4 * GCNT + t], red);
  if (t == 0) {
    const float db = SB / fmaxf(CB, 1.0f);
    const float dp = SP / fmaxf(CP, 1.0f);
    const float l_cdd = (CB > 0.0f && CP > 0.0f) ? fmaxf(CMARG + db - dp, 0.0f) : 0.0f;
    const float l_pcc = L * (1.0f / GCNT);
    // LAMBDA_CD = 0, LAMBDA_CDD = 1, LAMBDA_PCC = 1
    out[0] = l_cdd + l_pcc;  // total
    out[1] = l_cdd;
    out[2] = l_pcc;
  }
}

extern "C" void kernel_launch(void* const* d_in, const int* in_sizes, int n_in,
                              void* d_out, int out_size, void* d_ws, size_t ws_size,
                              hipStream_t stream) {
  const float* zr     = (const float*)d_in[0];
  const float* zv     = (const float*)d_in[1];
  const int*   labels = (const int*)d_in[2];
  // d_in[3] = groups: contiguous equal-size groups, derivable -> unused
  const int*   varl   = (const int*)d_in[4];
  float* out  = (float*)d_out;
  float* dvec = out + 3;          // out[3..] = d (N floats)
  float* gws  = (float*)d_ws;     // G*5 floats of group partials

  dot_kernel<<<NTOT / 4, 256, 0, stream>>>(zr, zv, dvec);
  group_kernel<<<GCNT, 256, 0, stream>>>(dvec, labels, varl, gws);
  final_kernel<<<1, 512, 0, stream>>>(gws, out);
}

// Round 2
// 114.518 us; speedup vs baseline: 1.1329x; 1.1329x over previous
//
#include <hip/hip_runtime.h>

#define NTOT   131072
#define DIMV   512
#define GCNT   512
#define NGRP   256
#define KMARG  0.02f
#define CMARG  2.0f
#define EPSC   1e-6f

typedef float f4 __attribute__((ext_vector_type(4)));

// Multi-value block reduction: reduces M floats across the block (NW wave64s).
// 2 barriers total regardless of M. Results broadcast back into v[0..M-1].
template <int NW, int M>
__device__ __forceinline__ void block_sum_m(float* v, float* red) {
  const int t = threadIdx.x;
#pragma unroll
  for (int m = 0; m < M; ++m) {
#pragma unroll
    for (int off = 32; off; off >>= 1) v[m] += __shfl_down(v[m], off, 64);
  }
  __syncthreads();  // WAR guard on red from previous call
  if ((t & 63) == 0) {
#pragma unroll
    for (int m = 0; m < M; ++m) red[(t >> 6) * M + m] = v[m];
  }
  __syncthreads();
#pragma unroll
  for (int m = 0; m < M; ++m) {
    float s = 0.0f;
#pragma unroll
    for (int i = 0; i < NW; ++i) s += red[i * M + m];
    v[m] = s;
  }
}

__device__ __forceinline__ float wave_sum(float v) {
#pragma unroll
  for (int off = 32; off; off >>= 1) v += __shfl_down(v, off, 64);
  return v;
}

// One wave per 2 rows (8x float4 in flight per wave); 4 waves/block -> 8 rows/block.
__global__ __launch_bounds__(256) void dot_kernel(const float* __restrict__ zr,
                                                  const float* __restrict__ zv,
                                                  float* __restrict__ dout) {
  const int wave = threadIdx.x >> 6;
  const int lane = threadIdx.x & 63;
  const int row0 = ((blockIdx.x << 2) + wave) << 1;
  const f4* r = (const f4*)zr + ((size_t)row0 << 7);  // 128 f4 per row
  const f4* v = (const f4*)zv + ((size_t)row0 << 7);
  f4 a0 = __builtin_nontemporal_load(r + lane);
  f4 b0 = __builtin_nontemporal_load(v + lane);
  f4 a1 = __builtin_nontemporal_load(r + lane + 64);
  f4 b1 = __builtin_nontemporal_load(v + lane + 64);
  f4 a2 = __builtin_nontemporal_load(r + lane + 128);
  f4 b2 = __builtin_nontemporal_load(v + lane + 128);
  f4 a3 = __builtin_nontemporal_load(r + lane + 192);
  f4 b3 = __builtin_nontemporal_load(v + lane + 192);
  f4 p = a0 * b0 + a1 * b1;
  f4 q = a2 * b2 + a3 * b3;
  float s0 = wave_sum(p.x + p.y + p.z + p.w);
  float s1 = wave_sum(q.x + q.y + q.z + q.w);
  if (lane == 0) {
    dout[row0]     = 1.0f - s0;
    dout[row0 + 1] = 1.0f - s1;
  }
}

// One 256-thread block per group. Sort-free: pairwise loop gives the rank
// loss directly (permutation-invariant) AND each element's stable rank;
// one LDS scatter by rank recovers the sorted-by-v order for the neighbor term.
__global__ __launch_bounds__(256) void group_kernel(const float* __restrict__ d,
                                                    const int* __restrict__ labels,
                                                    const int* __restrict__ varl,
                                                    float* __restrict__ gout) {
  __shared__ float  red[4 * 4];
  __shared__ float2 skv[NGRP];
  __shared__ float  sdat[NGRP];
  const int g = blockIdx.x, t = threadIdx.x;
  const int idx = g * NGRP + t;
  const float dv  = d[idx];
  const float vv  = (float)varl[idx];   // var_lens < 10000 -> exact in fp32
  const int   lab = labels[idx];

  skv[t] = make_float2(vv, dv);

  // Phase A: sum d, sum v, label-0 d-sum, label-0 count
  float sA[4] = {dv, vv, (lab == 0) ? dv : 0.0f, (lab == 0) ? 1.0f : 0.0f};
  block_sum_m<4, 4>(sA, red);
  const float sumd = sA[0], sumv = sA[1], sb = sA[2], cb = sA[3];
  const float md = sumd * (1.0f / NGRP), mv = sumv * (1.0f / NGRP);

  // Phase B: central moments (two-pass for precision)
  const float vdev = vv - mv, ddev = dv - md;
  float sB[3] = {vdev * vdev, ddev * ddev, vdev * ddev};
  block_sum_m<4, 3>(sB, red);
  const float svv = sB[0], sdd = sB[1], svd = sB[2];
  const float vstd = sqrtf(svv * (1.0f / (NGRP - 1)));
  const float dstd = sqrtf(sdd * (1.0f / (NGRP - 1)));
  const float iv = 1.0f / (vstd + EPSC), id = 1.0f / (dstd + EPSC);
  // sum((vz - dz)^2) = svv*iv^2 + sdd*id^2 - 2*svd*iv*id  (algebraically exact)
  float corr = (svv * iv * iv + sdd * id * id - 2.0f * svd * iv * id) * (1.0f / NGRP);
  corr = (vstd > 0.0f && dstd > 0.0f) ? corr : 0.0f;

  // Pairwise loop: rank loss (permutation-invariant -> unsorted ok) + stable rank
  __syncthreads();  // skv visible
  int rank = 0;
  float pc = 0.0f, ps = 0.0f;
  const float pre = KMARG + dv;
  for (int j = 0; j < NGRP; ++j) {
    const float2 kv = skv[j];          // LDS broadcast (same addr all lanes)
    const float vj = kv.x, dj = kv.y;
    if (vj > vv) {                     // v_j > v_i : pair contributes
      pc += 1.0f;
      ps += fmaxf(pre - dj, 0.0f);     // relu(K - (d_j - d_i))
    }
    rank += (vj < vv || (vj == vv && j < t)) ? 1 : 0;  // stable rank
  }
  sdat[rank] = dv;                     // scatter into sorted-by-v order
  __syncthreads();
  const float nv = (t < NGRP - 1) ? fmaxf(sdat[t] - sdat[t + 1] + KMARG, 0.0f) : 0.0f;

  float sC[3] = {ps, pc, nv};
  block_sum_m<4, 3>(sC, red);
  const float rank_loss = (sC[1] > 0.0f) ? sC[0] / fmaxf(sC[1], 1.0f) : 0.0f;
  const float neigh = sC[2] * (1.0f / (NGRP - 1));

  if (t == 0) {
    gout[g]            = corr + neigh + rank_loss;
    gout[GCNT + g]     = sb;
    gout[2 * GCNT + g] = cb;
    gout[3 * GCNT + g] = sumd;
  }
}

__global__ __launch_bounds__(512) void final_kernel(const float* __restrict__ gout,
                                                    float* __restrict__ out) {
  __shared__ float red[8 * 4];
  const int t = threadIdx.x;
  float s[4] = {gout[t], gout[GCNT + t], gout[2 * GCNT + t], gout[3 * GCNT + t]};
  block_sum_m<8, 4>(s, red);
  if (t == 0) {
    const float L = s[0], SB = s[1], CB = s[2], SumD = s[3];
    const float SP = SumD - SB;
    const float CP = (float)NTOT - CB;
    const float db = SB / fmaxf(CB, 1.0f);
    const float dp = SP / fmaxf(CP, 1.0f);
    const float l_cdd = (CB > 0.0f && CP > 0.0f) ? fmaxf(CMARG + db - dp, 0.0f) : 0.0f;
    const float l_pcc = L * (1.0f / GCNT);
    out[0] = l_cdd + l_pcc;   // LAMBDA_CD = 0
    out[1] = l_cdd;
    out[2] = l_pcc;
  }
}

extern "C" void kernel_launch(void* const* d_in, const int* in_sizes, int n_in,
                              void* d_out, int out_size, void* d_ws, size_t ws_size,
                              hipStream_t stream) {
  const float* zr     = (const float*)d_in[0];
  const float* zv     = (const float*)d_in[1];
  const int*   labels = (const int*)d_in[2];
  // d_in[3] = groups: contiguous equal-size -> derivable, unused
  const int*   varl   = (const int*)d_in[4];
  float* out  = (float*)d_out;
  float* dvec = out + 3;          // out[3..] = d (N floats)
  float* gws  = (float*)d_ws;     // G*4 floats of group partials

  dot_kernel<<<NTOT / 8, 256, 0, stream>>>(zr, zv, dvec);
  group_kernel<<<GCNT, 256, 0, stream>>>(dvec, labels, varl, gws);
  final_kernel<<<1, 512, 0, stream>>>(gws, out);
}

// Round 3
// 113.818 us; speedup vs baseline: 1.1399x; 1.0061x over previous
//
#include <hip/hip_runtime.h>

#define NTOT   131072
#define DIMV   512
#define GCNT   512
#define NGRP   256
#define KMARG  0.02f
#define CMARG  2.0f
#define EPSC   1e-6f

typedef float f4 __attribute__((ext_vector_type(4)));

// Multi-value block reduction: reduces M floats across the block (NW wave64s).
// 2 barriers total regardless of M. Results broadcast back into v[0..M-1].
template <int NW, int M>
__device__ __forceinline__ void block_sum_m(float* v, float* red) {
  const int t = threadIdx.x;
#pragma unroll
  for (int m = 0; m < M; ++m) {
#pragma unroll
    for (int off = 32; off; off >>= 1) v[m] += __shfl_down(v[m], off, 64);
  }
  __syncthreads();  // WAR guard on red from previous call
  if ((t & 63) == 0) {
#pragma unroll
    for (int m = 0; m < M; ++m) red[(t >> 6) * M + m] = v[m];
  }
  __syncthreads();
#pragma unroll
  for (int m = 0; m < M; ++m) {
    float s = 0.0f;
#pragma unroll
    for (int i = 0; i < NW; ++i) s += red[i * M + m];
    v[m] = s;
  }
}

__device__ __forceinline__ float wave_sum(float v) {
#pragma unroll
  for (int off = 32; off; off >>= 1) v += __shfl_down(v, off, 64);
  return v;
}

// One block per group. Phase 1: stream this group's 256 rows (1 MB) computing
// cosine distances into LDS (+ global d output). Phase 2: group losses from LDS.
// No inter-kernel dependency: block g only ever needs rows of group g.
__global__ __launch_bounds__(256) void fused_kernel(const float* __restrict__ zr,
                                                    const float* __restrict__ zv,
                                                    const int* __restrict__ labels,
                                                    const int* __restrict__ varl,
                                                    float* __restrict__ dvec,
                                                    float* __restrict__ gout) {
  __shared__ float  red[4 * 4];
  __shared__ float  sd[NGRP];
  __shared__ float2 skv[NGRP];
  __shared__ float  sdat[NGRP];
  const int g = blockIdx.x, t = threadIdx.x;
  const int wave = t >> 6, lane = t & 63;

  // ---- Phase 1: dots. Each wave: 2 rows/iter, 8 rows/block/iter, 32 iters ----
  const size_t rowbase = (size_t)g * NGRP;
#pragma unroll 2
  for (int it = 0; it < NGRP / 8; ++it) {
    const int rg = it * 8 + wave * 2;            // row within group (2 rows)
    const size_t row0 = rowbase + rg;
    const f4* r = (const f4*)zr + (row0 << 7);   // 128 f4 per row
    const f4* v = (const f4*)zv + (row0 << 7);
    f4 a0 = __builtin_nontemporal_load(r + lane);
    f4 b0 = __builtin_nontemporal_load(v + lane);
    f4 a1 = __builtin_nontemporal_load(r + lane + 64);
    f4 b1 = __builtin_nontemporal_load(v + lane + 64);
    f4 a2 = __builtin_nontemporal_load(r + lane + 128);
    f4 b2 = __builtin_nontemporal_load(v + lane + 128);
    f4 a3 = __builtin_nontemporal_load(r + lane + 192);
    f4 b3 = __builtin_nontemporal_load(v + lane + 192);
    f4 p = a0 * b0 + a1 * b1;
    f4 q = a2 * b2 + a3 * b3;
    float s0 = wave_sum(p.x + p.y + p.z + p.w);
    float s1 = wave_sum(q.x + q.y + q.z + q.w);
    if (lane == 0) {
      const float d0 = 1.0f - s0, d1 = 1.0f - s1;
      sd[rg]     = d0;
      sd[rg + 1] = d1;
      dvec[row0]     = d0;
      dvec[row0 + 1] = d1;
    }
  }
  __syncthreads();

  // ---- Phase 2: group losses (all from LDS/registers) ----
  const int idx = g * NGRP + t;
  const float dv  = sd[t];
  const float vv  = (float)varl[idx];   // var_lens < 10000 -> exact in fp32
  const int   lab = labels[idx];

  skv[t] = make_float2(vv, dv);

  // A: sum d, sum v, label-0 d-sum, label-0 count
  float sA[4] = {dv, vv, (lab == 0) ? dv : 0.0f, (lab == 0) ? 1.0f : 0.0f};
  block_sum_m<4, 4>(sA, red);
  const float sumd = sA[0], sumv = sA[1], sb = sA[2], cb = sA[3];
  const float md = sumd * (1.0f / NGRP), mv = sumv * (1.0f / NGRP);

  // B: central moments (two-pass), corr loss in closed form
  const float vdev = vv - mv, ddev = dv - md;
  float sB[3] = {vdev * vdev, ddev * ddev, vdev * ddev};
  block_sum_m<4, 3>(sB, red);
  const float svv = sB[0], sdd = sB[1], svd = sB[2];
  const float vstd = sqrtf(svv * (1.0f / (NGRP - 1)));
  const float dstd = sqrtf(sdd * (1.0f / (NGRP - 1)));
  const float iv = 1.0f / (vstd + EPSC), id = 1.0f / (dstd + EPSC);
  float corr = (svv * iv * iv + sdd * id * id - 2.0f * svd * iv * id) * (1.0f / NGRP);
  corr = (vstd > 0.0f && dstd > 0.0f) ? corr : 0.0f;

  // C: pairwise rank loss (permutation-invariant) + stable rank for neighbor term
  int rank = 0;
  float pc = 0.0f, ps = 0.0f;
  const float pre = KMARG + dv;
  for (int j = 0; j < NGRP; ++j) {
    const float2 kv = skv[j];          // LDS broadcast
    const float vj = kv.x, dj = kv.y;
    if (vj > vv) {
      pc += 1.0f;
      ps += fmaxf(pre - dj, 0.0f);
    }
    rank += (vj < vv || (vj == vv && j < t)) ? 1 : 0;  // stable rank
  }
  sdat[rank] = dv;                     // scatter into sorted-by-v order
  __syncthreads();
  const float nv = (t < NGRP - 1) ? fmaxf(sdat[t] - sdat[t + 1] + KMARG, 0.0f) : 0.0f;

  float sC[3] = {ps, pc, nv};
  block_sum_m<4, 3>(sC, red);
  const float rank_loss = (sC[1] > 0.0f) ? sC[0] / fmaxf(sC[1], 1.0f) : 0.0f;
  const float neigh = sC[2] * (1.0f / (NGRP - 1));

  if (t == 0) {
    gout[g]            = corr + neigh + rank_loss;
    gout[GCNT + g]     = sb;
    gout[2 * GCNT + g] = cb;
    gout[3 * GCNT + g] = sumd;
  }
}

__global__ __launch_bounds__(512) void final_kernel(const float* __restrict__ gout,
                                                    float* __restrict__ out) {
  __shared__ float red[8 * 4];
  const int t = threadIdx.x;
  float s[4] = {gout[t], gout[GCNT + t], gout[2 * GCNT + t], gout[3 * GCNT + t]};
  block_sum_m<8, 4>(s, red);
  if (t == 0) {
    const float L = s[0], SB = s[1], CB = s[2], SumD = s[3];
    const float SP = SumD - SB;
    const float CP = (float)NTOT - CB;
    const float db = SB / fmaxf(CB, 1.0f);
    const float dp = SP / fmaxf(CP, 1.0f);
    const float l_cdd = (CB > 0.0f && CP > 0.0f) ? fmaxf(CMARG + db - dp, 0.0f) : 0.0f;
    const float l_pcc = L * (1.0f / GCNT);
    out[0] = l_cdd + l_pcc;   // LAMBDA_CD = 0
    out[1] = l_cdd;
    out[2] = l_pcc;
  }
}

extern "C" void kernel_launch(void* const* d_in, const int* in_sizes, int n_in,
                              void* d_out, int out_size, void* d_ws, size_t ws_size,
                              hipStream_t stream) {
  const float* zr     = (const float*)d_in[0];
  const float* zv     = (const float*)d_in[1];
  const int*   labels = (const int*)d_in[2];
  // d_in[3] = groups: contiguous equal-size -> derivable, unused
  const int*   varl   = (const int*)d_in[4];
  float* out  = (float*)d_out;
  float* dvec = out + 3;          // out[3..] = d (N floats)
  float* gws  = (float*)d_ws;     // G*4 floats of group partials

  fused_kernel<<<GCNT, 256, 0, stream>>>(zr, zv, labels, varl, dvec, gws);
  final_kernel<<<1, 512, 0, stream>>>(gws, out);
}